// Round 7
// baseline (377.196 us; speedup 1.0000x reference)
//
#include <hip/hip_runtime.h>
#include <cstdint>
#include <cstddef>

#define NB 4
#define NG 8
#define NCELL 331776   // 48*48*48*3
#define NTILE 1296     // 256-cell tiles per batch
#define KTOP 800
#define TCAP 4096      // per-batch tie-buffer capacity (expected ~28 ties)
#define SBLK 81        // sum_kernel blocks per batch (81 * 4096 = NCELL)

struct WsHeader {
  float pos_sum[NB];
  float reg_sum[NB];
  int   npos[NB];
  int   neg_cnt[NB];
  int   take_all[NB];
  int   jj[NB];        // exact 16-bit threshold bucket (key >> 16)
  int   k_tie[NB];     // #ties to take at bucket jj
  float neg_sum[NB];
  int   tie_cnt[NB];
  int   done;
};
// ws layout: [WsHeader @0][hist16 NB*65536 @1024B][ties NB*TCAP][keys NB*NCELL]

__device__ __forceinline__ float softplus0(float x) {
  // _bce_logits(x, 0) = max(x,0) + log1p(exp(-|x|))
  return fmaxf(x, 0.f) + log1pf(expf(-fabsf(x)));
}
__device__ __forceinline__ unsigned int f2key(float f) {
  unsigned int u = __float_as_uint(f);
  return (u & 0x80000000u) ? ~u : (u | 0x80000000u);
}
__device__ __forceinline__ float key2f(unsigned int k) {
  unsigned int u = (k & 0x80000000u) ? (k & 0x7fffffffu) : ~k;
  return __uint_as_float(u);
}
__device__ __forceinline__ float sl1(float x) {
  float ax = fabsf(x);
  return ax < 1.f ? 0.5f * x * x : ax - 0.5f;
}

__global__ void init_kernel(unsigned int* __restrict__ wsbase, int nwords) {
  for (int i = blockIdx.x * blockDim.x + threadIdx.x; i < nwords; i += gridDim.x * blockDim.x)
    wsbase[i] = 0u;
}

// Per-cell loss terms + dense key write + 16-bit global histogram.
// pred staged through LDS via coalesced float4 loads (stride-5 LDS reads are
// 2-way bank-aliased = free per m136).
__global__ __launch_bounds__(256) void main_kernel(const float* __restrict__ pred,
                                                   const float* __restrict__ tgt,
                                                   WsHeader* __restrict__ ws,
                                                   unsigned int* __restrict__ hist16,
                                                   unsigned int* __restrict__ keys) {
  __shared__ __align__(16) float ld[1280];     // 256 cells x 5 floats
  __shared__ float gt[NG * 4];
  __shared__ float s_psum, s_rsum;
  __shared__ int s_np;
  const int b = blockIdx.y;
  const int tile = blockIdx.x;
  const int tid = threadIdx.x;

  if (tid < NG * 4) gt[tid] = tgt[b * NG * 4 + tid];
  if (tid == 0) { s_psum = 0.f; s_rsum = 0.f; s_np = 0; }

  const float4* p4 = (const float4*)(pred + ((size_t)b * NCELL + (size_t)tile * 256) * 5);
  float4* ld4 = (float4*)ld;
  ld4[tid] = p4[tid];
  if (tid < 64) ld4[256 + tid] = p4[256 + tid];
  __syncthreads();

  const int i = tile * 256 + tid;
  int a = i % 3; int t = i / 3;
  int w = t % 48; t /= 48;
  int h = t % 48; int d = t / 48;
  const float cx = w * 4.f + 2.f, cy = h * 4.f + 2.f, cz = d * 4.f + 2.f;
  const float anch[3] = {5.f, 10.f, 20.f};
  const float an = anch[a];
  const float r1 = an * 0.5f;
  const float an3 = an * an * an;

  float best = -1.f; int arg = 0;
#pragma unroll
  for (int g = 0; g < NG; ++g) {
    float gx = gt[g * 4 + 0], gy = gt[g * 4 + 1], gz = gt[g * 4 + 2], gd = gt[g * 4 + 3];
    float r2 = gd * 0.5f;
    float ix = fmaxf(fminf(cx + r1, gx + r2) - fmaxf(cx - r1, gx - r2), 0.f);
    float iy = fmaxf(fminf(cy + r1, gy + r2) - fmaxf(cy - r1, gy - r2), 0.f);
    float iz = fmaxf(fminf(cz + r1, gz + r2) - fmaxf(cz - r1, gz - r2), 0.f);
    float iv = (ix * iy) * iz;
    float un = (an3 + gd * gd * gd) - iv;
    float iou = iv / (un + 1e-6f);
    if (iou > best) { best = iou; arg = g; }   // strict > == first-argmax
  }
  const bool pos = best > 0.5f;
  const bool neg = best < 0.02f;
  const float conf = ld[tid * 5];

  unsigned int key = 0u;   // sentinel: -NaN bit pattern, unreachable as real key
  if (neg) {
    key = f2key(conf);
    atomicAdd(&hist16[((unsigned)b << 16) | (key >> 16)], 1u);   // fire-and-forget
  }
  keys[(size_t)b * NCELL + i] = key;

  if (pos) {
    float bce1 = fmaxf(conf, 0.f) - conf + log1pf(expf(-fabsf(conf)));
    float mgx = gt[arg * 4 + 0], mgy = gt[arg * 4 + 1], mgz = gt[arg * 4 + 2], mgd = gt[arg * 4 + 3];
    float t0 = (mgx - cx) / an, t1 = (mgy - cy) / an, t2 = (mgz - cz) / an;
    float t3 = logf(mgd / an);
    float d0 = ld[tid * 5 + 1] - t0;
    float d1 = ld[tid * 5 + 2] - t1;
    float d2 = ld[tid * 5 + 3] - t2;
    float d3 = ld[tid * 5 + 4] - t3;
    float rl = sl1(d0) + sl1(d1) + sl1(d2) + sl1(d3);
    atomicAdd(&s_psum, bce1);
    atomicAdd(&s_rsum, rl);
    atomicAdd(&s_np, 1);
  }
  __syncthreads();
  if (tid == 0 && s_np > 0) {        // rare: fire-and-forget, most blocks skip
    atomicAdd(&ws->pos_sum[b], s_psum);
    atomicAdd(&ws->reg_sum[b], s_rsum);
    atomicAdd(&ws->npos[b], s_np);
  }
}

// One block per batch: single scan of the 65536-bin histogram -> exact 16-bit
// threshold bucket jj, tie count k_tie, total M.
__global__ __launch_bounds__(1024) void threshold_kernel(const unsigned int* __restrict__ hist16,
                                                         WsHeader* __restrict__ ws) {
  const int b = blockIdx.x;
  const int tid = threadIdx.x;
  const unsigned int* H = hist16 + ((unsigned)b << 16);
  __shared__ unsigned int L[1024];

  const int base = tid * 64;
  unsigned int local = 0;
  for (int i2 = 0; i2 < 64; ++i2) local += H[base + i2];
  L[tid] = local;
  __syncthreads();
  // inclusive suffix scan: L[t] = sum_{t' >= t} local[t']
  for (int dlt = 1; dlt < 1024; dlt <<= 1) {
    unsigned int v = (tid + dlt < 1024) ? L[tid + dlt] : 0u;
    __syncthreads();
    L[tid] += v;
    __syncthreads();
  }
  const unsigned int M = L[0];
  if (tid == 0) {
    ws->neg_cnt[b] = (int)M;
    ws->take_all[b] = (M < KTOP) ? 1 : 0;
  }
  const unsigned int sufAfter = (tid < 1023) ? L[tid + 1] : 0u;   // strictly after my chunk
  if (M >= KTOP && L[tid] >= (unsigned)KTOP && sufAfter < (unsigned)KTOP) {
    // the crossing bin is inside this thread's 64 bins
    unsigned int run = sufAfter;          // count strictly above current bin
    for (int vi = 63; vi >= 0; --vi) {
      unsigned int hh = H[base + vi];
      unsigned int nrun = run + hh;       // = S(base+vi)
      if (nrun >= (unsigned)KTOP) {
        ws->jj[b] = base + vi;
        ws->k_tie[b] = KTOP - (int)run;   // ties to take at this bucket
        break;
      }
      run = nrun;
    }
  }
}

// Grid-wide: sum softplus over keys with top16 > jj (block reduce + one atomic),
// compact the ~k_tie-bin ties into a tiny buffer. Last-done block ranks ties
// exactly (n ~ 28) and writes the final outputs.
__global__ __launch_bounds__(256) void sum_kernel(const unsigned int* __restrict__ keys,
                                                  WsHeader* __restrict__ ws,
                                                  unsigned int* __restrict__ ties,
                                                  float* __restrict__ out) {
  const int b = blockIdx.y;
  const int tl = blockIdx.x;
  const int tid = threadIdx.x;
  __shared__ unsigned int tk[TCAP];
  __shared__ float wred[4];
  __shared__ int sh_last;

  const bool ta = ws->take_all[b] != 0;
  const unsigned int jthr = (unsigned int)ws->jj[b];

  const uint4* k4 = (const uint4*)(keys + (size_t)b * NCELL);
  const int base4 = tl * 1024;   // 81 blocks x 1024 uint4 = NCELL/4
  float s = 0.f;
#pragma unroll
  for (int it = 0; it < 4; ++it) {
    uint4 kk = k4[base4 + it * 256 + tid];
    unsigned int kv;
#pragma unroll
    for (int c4 = 0; c4 < 4; ++c4) {
      kv = (c4 == 0) ? kk.x : (c4 == 1) ? kk.y : (c4 == 2) ? kk.z : kk.w;
      if (ta) {
        if (kv != 0u) s += softplus0(key2f(kv));
      } else {
        unsigned int t16 = kv >> 16;
        if (t16 > jthr) s += softplus0(key2f(kv));
        else if (kv != 0u && t16 == jthr) {
          int slot = atomicAdd(&ws->tie_cnt[b], 1);
          if (slot < TCAP) ties[b * TCAP + slot] = kv;
        }
      }
    }
  }
  for (int o = 32; o > 0; o >>= 1) s += __shfl_down(s, o);
  if ((tid & 63) == 0) wred[tid >> 6] = s;
  __syncthreads();
  if (tid == 0) {
    float sblk = wred[0] + wred[1] + wred[2] + wred[3];
    if (sblk != 0.f) atomicAdd(&ws->neg_sum[b], sblk);
    __threadfence();
    int old = atomicAdd(&ws->done, 1);
    sh_last = (old == SBLK * NB - 1) ? 1 : 0;
  }
  __syncthreads();
  if (!sh_last) return;
  __threadfence();   // acquire: all blocks' neg_sum / tie writes visible

  // ---- exact tie resolution + combine (one block, ~1 us) ----
  for (int bb = 0; bb < NB; ++bb) {
    if (ws->take_all[bb]) continue;
    int n = ws->tie_cnt[bb]; if (n > TCAP) n = TCAP;
    const int kt = ws->k_tie[bb];
    for (int i2 = tid; i2 < n; i2 += 256) tk[i2] = ties[bb * TCAP + i2];
    __syncthreads();
    float sv = 0.f;
    for (int i2 = tid; i2 < n; i2 += 256) {
      unsigned int kv = tk[i2];
      int rank = 0;
      for (int j2 = 0; j2 < n; ++j2) {
        unsigned int o2 = tk[j2];
        rank += (o2 > kv) || (o2 == kv && j2 < i2);
      }
      if (rank < kt) sv += softplus0(key2f(kv));
    }
    for (int o = 32; o > 0; o >>= 1) sv += __shfl_down(sv, o);
    if ((tid & 63) == 0) wred[tid >> 6] = sv;
    __syncthreads();
    if (tid == 0) ws->neg_sum[bb] += wred[0] + wred[1] + wred[2] + wred[3];
    __syncthreads();
  }
  if (tid == 0) {
    float cls_s = 0.f, reg_s = 0.f, np_s = 0.f;
    for (int bb = 0; bb < NB; ++bb) {
      int np = ws->npos[bb];
      float pos_l = (np > 0) ? 5.f * ws->pos_sum[bb] / (float)np : 0.f;
      int Mb = ws->neg_cnt[bb];
      float kcnt = fminf((float)Mb, (float)KTOP);
      float neg_l = (kcnt > 0.f) ? ws->neg_sum[bb] / fmaxf(kcnt, 1.f) : 0.f;
      float reg_l = (np > 0) ? ws->reg_sum[bb] / (4.f * (float)np) : 0.f;
      cls_s += pos_l + neg_l;
      reg_s += reg_l;
      np_s += (float)np;
    }
    float cls = cls_s * 0.25f;
    float reg = reg_s * 0.25f;
    out[0] = cls + 0.5f * reg;
    out[1] = cls;
    out[2] = reg;
    out[3] = np_s;
  }
}

extern "C" void kernel_launch(void* const* d_in, const int* in_sizes, int n_in,
                              void* d_out, int out_size, void* d_ws, size_t ws_size,
                              hipStream_t stream) {
  const float* pred = (const float*)d_in[0];
  const float* tgt  = (const float*)d_in[1];
  WsHeader* ws = (WsHeader*)d_ws;
  unsigned int* hist16 = (unsigned int*)((char*)d_ws + 1024);
  unsigned int* ties   = hist16 + (size_t)NB * 65536;
  unsigned int* keys   = ties + (size_t)NB * TCAP;
  float* out = (float*)d_out;

  // zero header + hist16 + tie buffers/counters (keys are fully overwritten)
  const int nzero = (1024 + NB * 65536 * 4 + NB * TCAP * 4) / 4;
  hipLaunchKernelGGL(init_kernel, dim3(128), dim3(256), 0, stream, (unsigned int*)d_ws, nzero);
  hipLaunchKernelGGL(main_kernel, dim3(NTILE, NB), dim3(256), 0, stream, pred, tgt, ws, hist16, keys);
  hipLaunchKernelGGL(threshold_kernel, dim3(NB), dim3(1024), 0, stream, hist16, ws);
  hipLaunchKernelGGL(sum_kernel, dim3(SBLK, NB), dim3(256), 0, stream, keys, ws, ties, out);
}

// Round 8
// 109.397 us; speedup vs baseline: 3.4480x; 3.4480x over previous
//
#include <hip/hip_runtime.h>
#include <cstdint>
#include <cstddef>

#define NB 4
#define NG 8
#define NCELL 331776   // 48*48*48*3
#define NTILE 1296     // 256-cell tiles per batch
#define KTOP 800
#define NREP 8         // global histogram replicas to spread atomic traffic
#define CAP 16384      // per-batch candidate buffer capacity (expected ~7.4k)
#define LCAP 12288     // candidates cached in LDS when m <= LCAP (48 KB)

struct WsHeader {
  float pos_sum[NB];
  float reg_sum[NB];
  int   npos[NB];
  int   neg_cnt[NB];
  int   take_all[NB];
  int   prefix8[NB];            // top-byte threshold bucket j
  int   k_rem[NB];              // KTOP - count(top byte > j)
  float neg_sum[NB];
  int   done;
  int   bucket_cnt[NB][16];     // one cacheline per batch
  unsigned int hist[NB][NREP][256];
};

__device__ __forceinline__ float softplus0(float x) {
  // _bce_logits(x, 0) = max(x,0) + log1p(exp(-|x|))
  return fmaxf(x, 0.f) + log1pf(expf(-fabsf(x)));
}
__device__ __forceinline__ unsigned int f2key(float f) {
  unsigned int u = __float_as_uint(f);
  return (u & 0x80000000u) ? ~u : (u | 0x80000000u);
}
__device__ __forceinline__ float key2f(unsigned int k) {
  unsigned int u = (k & 0x80000000u) ? (k & 0x7fffffffu) : ~k;
  return __uint_as_float(u);
}
__device__ __forceinline__ float sl1(float x) {
  float ax = fabsf(x);
  return ax < 1.f ? 0.5f * x * x : ax - 0.5f;
}

__global__ void init_kernel(WsHeader* ws) {
  unsigned int* p = (unsigned int*)ws;
  const int nw = (int)(sizeof(WsHeader) / 4);
  for (int i = blockIdx.x * blockDim.x + threadIdx.x; i < nw; i += gridDim.x * blockDim.x)
    p[i] = 0u;
}

// Per-cell loss terms + dense key write + top-byte histogram.
// pred staged through LDS via coalesced float4 loads (stride-5 LDS reads are
// 2-way bank-aliased = free per m136); 4 LDS hist replicas (stride 257) are
// flushed as 256 aggregated atomics/block into NREP global replicas —
// NEVER per-element global atomics (R1/R7 lesson: hot-line RMW serializes).
__global__ __launch_bounds__(256) void main_kernel(const float* __restrict__ pred,
                                                   const float* __restrict__ tgt,
                                                   WsHeader* __restrict__ ws,
                                                   unsigned int* __restrict__ keys) {
  __shared__ __align__(16) float ld[1280];     // 256 cells x 5 floats
  __shared__ float gt[NG * 4];
  __shared__ unsigned int lhist[4 * 257];      // 4 replicas, stride 257
  __shared__ float s_psum, s_rsum;
  __shared__ int s_np;
  const int b = blockIdx.y;
  const int tile = blockIdx.x;
  const int tid = threadIdx.x;

  if (tid < NG * 4) gt[tid] = tgt[b * NG * 4 + tid];
  for (int e = tid; e < 4 * 257; e += 256) lhist[e] = 0u;
  if (tid == 0) { s_psum = 0.f; s_rsum = 0.f; s_np = 0; }

  const float4* p4 = (const float4*)(pred + ((size_t)b * NCELL + (size_t)tile * 256) * 5);
  float4* ld4 = (float4*)ld;
  ld4[tid] = p4[tid];
  if (tid < 64) ld4[256 + tid] = p4[256 + tid];
  __syncthreads();

  const int i = tile * 256 + tid;
  int a = i % 3; int t = i / 3;
  int w = t % 48; t /= 48;
  int h = t % 48; int d = t / 48;
  const float cx = w * 4.f + 2.f, cy = h * 4.f + 2.f, cz = d * 4.f + 2.f;
  const float anch[3] = {5.f, 10.f, 20.f};
  const float an = anch[a];
  const float r1 = an * 0.5f;
  const float an3 = an * an * an;

  float best = -1.f; int arg = 0;
#pragma unroll
  for (int g = 0; g < NG; ++g) {
    float gx = gt[g * 4 + 0], gy = gt[g * 4 + 1], gz = gt[g * 4 + 2], gd = gt[g * 4 + 3];
    float r2 = gd * 0.5f;
    float ix = fmaxf(fminf(cx + r1, gx + r2) - fmaxf(cx - r1, gx - r2), 0.f);
    float iy = fmaxf(fminf(cy + r1, gy + r2) - fmaxf(cy - r1, gy - r2), 0.f);
    float iz = fmaxf(fminf(cz + r1, gz + r2) - fmaxf(cz - r1, gz - r2), 0.f);
    float iv = (ix * iy) * iz;
    float un = (an3 + gd * gd * gd) - iv;
    float iou = iv / (un + 1e-6f);
    if (iou > best) { best = iou; arg = g; }   // strict > == first-argmax
  }
  const bool pos = best > 0.5f;
  const bool neg = best < 0.02f;
  const float conf = ld[tid * 5];

  unsigned int key = 0u;   // sentinel: -NaN bit pattern, unreachable as real key
  if (neg) {
    key = f2key(conf);
    atomicAdd(&lhist[(tid & 3) * 257 + (key >> 24)], 1u);
  }
  keys[(size_t)b * NCELL + i] = key;

  if (pos) {
    float bce1 = fmaxf(conf, 0.f) - conf + log1pf(expf(-fabsf(conf)));
    float mgx = gt[arg * 4 + 0], mgy = gt[arg * 4 + 1], mgz = gt[arg * 4 + 2], mgd = gt[arg * 4 + 3];
    float t0 = (mgx - cx) / an, t1 = (mgy - cy) / an, t2 = (mgz - cz) / an;
    float t3 = logf(mgd / an);
    float d0 = ld[tid * 5 + 1] - t0;
    float d1 = ld[tid * 5 + 2] - t1;
    float d2 = ld[tid * 5 + 3] - t2;
    float d3 = ld[tid * 5 + 4] - t3;
    float rl = sl1(d0) + sl1(d1) + sl1(d2) + sl1(d3);
    atomicAdd(&s_psum, bce1);
    atomicAdd(&s_rsum, rl);
    atomicAdd(&s_np, 1);
  }
  __syncthreads();

  unsigned int c = lhist[tid] + lhist[257 + tid] + lhist[514 + tid] + lhist[771 + tid];
  if (c) atomicAdd(&ws->hist[b][blockIdx.x & (NREP - 1)][tid], c);
  if (tid == 0 && s_np > 0) {        // rare: fire-and-forget, most blocks skip
    atomicAdd(&ws->pos_sum[b], s_psum);
    atomicAdd(&ws->reg_sum[b], s_rsum);
    atomicAdd(&ws->npos[b], s_np);
  }
}

// Grid-parallel: each block redundantly finds the 8-bit threshold bucket j from
// the histogram, then compacts keys with top8 >= j into the small bucket buffer.
// Publishes j and k_rem so final can skip its degenerate radix pass 0.
__global__ __launch_bounds__(256) void compact_kernel(const unsigned int* __restrict__ keys,
                                                      WsHeader* __restrict__ ws,
                                                      unsigned int* __restrict__ bucket) {
  const int b = blockIdx.y;
  const int tid = threadIdx.x;
  __shared__ unsigned int A[256];
  __shared__ unsigned int cnts[256];
  __shared__ int sh_j, sh_base;

  unsigned int s = 0;
#pragma unroll
  for (int r = 0; r < NREP; ++r) s += ws->hist[b][r][tid];
  A[tid] = s;
  __syncthreads();
  for (int dlt = 1; dlt < 256; dlt <<= 1) {   // inclusive suffix scan
    unsigned int v = (tid + dlt < 256) ? A[tid + dlt] : 0u;
    __syncthreads();
    A[tid] += v;
    __syncthreads();
  }
  const int M = (int)A[0];
  const bool ta = (M < KTOP);
  if (!ta && A[tid] >= (unsigned)KTOP && (tid == 255 || A[tid + 1] < (unsigned)KTOP))
    sh_j = tid;
  __syncthreads();
  const unsigned int jthr = ta ? 0u : (unsigned int)sh_j;
  if (tid == 0 && blockIdx.x == 0) {
    ws->neg_cnt[b] = M;
    ws->take_all[b] = ta ? 1 : 0;
    ws->prefix8[b] = (int)jthr;
    int above = (!ta && jthr < 255u) ? (int)A[jthr + 1] : 0;
    ws->k_rem[b] = ta ? 0 : (KTOP - above);
  }

  const uint4* k4 = (const uint4*)(keys + (size_t)b * NCELL);
  const int base4 = blockIdx.x * 1024;   // 81 blocks x 1024 uint4 = NCELL/4
  int cnt = 0;
#pragma unroll
  for (int it = 0; it < 4; ++it) {
    uint4 kk = k4[base4 + it * 256 + tid];
    cnt += (kk.x != 0u && (kk.x >> 24) >= jthr);
    cnt += (kk.y != 0u && (kk.y >> 24) >= jthr);
    cnt += (kk.z != 0u && (kk.z >> 24) >= jthr);
    cnt += (kk.w != 0u && (kk.w >> 24) >= jthr);
  }
  cnts[tid] = (unsigned int)cnt;
  __syncthreads();
  for (int dlt = 1; dlt < 256; dlt <<= 1) {   // inclusive prefix scan
    unsigned int v = (tid >= dlt) ? cnts[tid - dlt] : 0u;
    __syncthreads();
    cnts[tid] += v;
    __syncthreads();
  }
  if (tid == 255) {
    int total = (int)cnts[255];
    sh_base = total ? atomicAdd(&ws->bucket_cnt[b][0], total) : 0;
  }
  __syncthreads();
  int off = sh_base + (int)cnts[tid] - cnt;   // exclusive rank + block base
#pragma unroll
  for (int it = 0; it < 4; ++it) {
    uint4 kk = k4[base4 + it * 256 + tid];
    unsigned int kv;
    kv = kk.x; if (kv != 0u && (kv >> 24) >= jthr) { if (off < CAP) bucket[(size_t)b * CAP + off] = kv; ++off; }
    kv = kk.y; if (kv != 0u && (kv >> 24) >= jthr) { if (off < CAP) bucket[(size_t)b * CAP + off] = kv; ++off; }
    kv = kk.z; if (kv != 0u && (kv >> 24) >= jthr) { if (off < CAP) bucket[(size_t)b * CAP + off] = kv; ++off; }
    kv = kk.w; if (kv != 0u && (kv >> 24) >= jthr) { if (off < CAP) bucket[(size_t)b * CAP + off] = kv; ++off; }
  }
}

// One block per batch: exact top-KTOP among the ~7.4k candidates.
// Radix starts at pass 1 (pass-0 bucket j + k_rem come from compact), candidates
// cached in LDS. Last block to finish also does the final combine.
__global__ __launch_bounds__(1024) void final_kernel(const unsigned int* __restrict__ bucket,
                                                     WsHeader* __restrict__ ws,
                                                     float* __restrict__ out) {
  const int b = blockIdx.x;
  const int tid = threadIdx.x;
  __shared__ unsigned int skeys[LCAP];
  __shared__ unsigned int h[256];
  __shared__ unsigned int A[256];
  __shared__ int sh_j;
  __shared__ float wred[16];
  __shared__ int sh_last;

  int m = ws->bucket_cnt[b][0]; if (m > CAP) m = CAP;
  const bool ta = ws->take_all[b] != 0;
  const unsigned int* kb = bucket + (size_t)b * CAP;
  const bool useLds = (m <= LCAP);
  if (useLds)
    for (int i = tid; i < m; i += 1024) skeys[i] = kb[i];
  __syncthreads();

  unsigned int T = 0u;
  int k = 0;
  if (!ta) {
    unsigned int P = ((unsigned int)ws->prefix8[b]) << 24;
    k = ws->k_rem[b];
    for (int pass = 1; pass < 4; ++pass) {
      const int sh = 24 - 8 * pass;
      const unsigned int hiMask = 0xFFFFFFFFu << (sh + 8);
      if (tid < 256) h[tid] = 0u;
      __syncthreads();
      for (int i = tid; i < m; i += 1024) {
        unsigned int kv = useLds ? skeys[i] : kb[i];
        if (((kv ^ P) & hiMask) == 0u) atomicAdd(&h[(kv >> sh) & 255u], 1u);
      }
      __syncthreads();
      if (tid < 256) A[tid] = h[tid];
      __syncthreads();
      for (int dlt = 1; dlt < 256; dlt <<= 1) {
        unsigned int v = (tid < 256 && tid + dlt < 256) ? A[tid + dlt] : 0u;
        __syncthreads();
        if (tid < 256) A[tid] += v;
        __syncthreads();
      }
      if (tid < 256 && A[tid] >= (unsigned)k && (tid == 255 || A[tid + 1] < (unsigned)k))
        sh_j = tid;
      __syncthreads();
      const int j = sh_j;
      k -= (j == 255) ? 0 : (int)A[j + 1];   // remove strictly-greater bins
      P |= ((unsigned int)j) << sh;
      __syncthreads();
    }
    T = P;   // exact threshold key; k = #ties to take at T
  }

  float v = 0.f;
  for (int i = tid; i < m; i += 1024) {
    unsigned int kv = useLds ? skeys[i] : kb[i];
    if (ta || kv > T) v += softplus0(key2f(kv));
  }
  for (int o = 32; o > 0; o >>= 1) v += __shfl_down(v, o);
  if ((tid & 63) == 0) wred[tid >> 6] = v;
  __syncthreads();
  if (tid == 0) {
    float sum = 0.f;
#pragma unroll
    for (int wv = 0; wv < 16; ++wv) sum += wred[wv];
    if (!ta) sum += (float)k * softplus0(key2f(T));
    ws->neg_sum[b] = sum;
    __threadfence();
    int old = atomicAdd(&ws->done, 1);
    sh_last = (old == NB - 1) ? 1 : 0;
  }
  __syncthreads();
  if (sh_last && tid == 0) {
    __threadfence();
    float cls_s = 0.f, reg_s = 0.f, np_s = 0.f;
    for (int bb = 0; bb < NB; ++bb) {
      int np = ws->npos[bb];
      float pos_l = (np > 0) ? 5.f * ws->pos_sum[bb] / (float)np : 0.f;
      int M = ws->neg_cnt[bb];
      float kcnt = fminf((float)M, (float)KTOP);
      float neg_l = (kcnt > 0.f) ? ws->neg_sum[bb] / fmaxf(kcnt, 1.f) : 0.f;
      float reg_l = (np > 0) ? ws->reg_sum[bb] / (4.f * (float)np) : 0.f;
      cls_s += pos_l + neg_l;
      reg_s += reg_l;
      np_s += (float)np;
    }
    float cls = cls_s * 0.25f;
    float reg = reg_s * 0.25f;
    out[0] = cls + 0.5f * reg;
    out[1] = cls;
    out[2] = reg;
    out[3] = np_s;
  }
}

extern "C" void kernel_launch(void* const* d_in, const int* in_sizes, int n_in,
                              void* d_out, int out_size, void* d_ws, size_t ws_size,
                              hipStream_t stream) {
  const float* pred = (const float*)d_in[0];
  const float* tgt  = (const float*)d_in[1];
  WsHeader* ws = (WsHeader*)d_ws;
  char* base = (char*)d_ws + ((sizeof(WsHeader) + 255) / 256) * 256;
  unsigned int* keys = (unsigned int*)base;
  unsigned int* bucket = (unsigned int*)(base + (size_t)NB * NCELL * 4);
  float* out = (float*)d_out;

  hipLaunchKernelGGL(init_kernel, dim3(16), dim3(256), 0, stream, ws);
  hipLaunchKernelGGL(main_kernel, dim3(NTILE, NB), dim3(256), 0, stream, pred, tgt, ws, keys);
  hipLaunchKernelGGL(compact_kernel, dim3(81, NB), dim3(256), 0, stream, keys, ws, bucket);
  hipLaunchKernelGGL(final_kernel, dim3(NB), dim3(1024), 0, stream, bucket, ws, out);
}

// Round 9
// 106.799 us; speedup vs baseline: 3.5318x; 1.0243x over previous
//
#include <hip/hip_runtime.h>
#include <cstdint>
#include <cstddef>

#define NB 4
#define NG 8
#define NCELL 331776   // 48*48*48*3
#define KTOP 800
#define NREP 8         // global histogram replicas to spread atomic traffic
#define CAP 16384      // per-batch candidate buffer capacity (expected ~7.4k)
#define LCAP 12288     // candidates cached in LDS when m <= LCAP (48 KB)
#define CPT 4          // cells per thread in main (ILP chains)
#define MBLK 324       // main blocks per batch: 324 * 256 * 4 = NCELL

struct WsHeader {
  float pos_sum[NB];
  float reg_sum[NB];
  int   npos[NB];
  int   neg_cnt[NB];
  int   take_all[NB];
  int   prefix8[NB];            // top-byte threshold bucket j
  int   k_rem[NB];              // KTOP - count(top byte > j)
  float neg_sum[NB];
  int   done;
  int   bucket_cnt[NB][16];     // one cacheline per batch
  unsigned int hist[NB][NREP][256];
};

__device__ __forceinline__ float softplus0(float x) {
  // _bce_logits(x, 0) = max(x,0) + log1p(exp(-|x|))
  return fmaxf(x, 0.f) + log1pf(expf(-fabsf(x)));
}
__device__ __forceinline__ unsigned int f2key(float f) {
  unsigned int u = __float_as_uint(f);
  return (u & 0x80000000u) ? ~u : (u | 0x80000000u);
}
__device__ __forceinline__ float key2f(unsigned int k) {
  unsigned int u = (k & 0x80000000u) ? (k & 0x7fffffffu) : ~k;
  return __uint_as_float(u);
}
__device__ __forceinline__ float sl1(float x) {
  float ax = fabsf(x);
  return ax < 1.f ? 0.5f * x * x : ax - 0.5f;
}

__global__ void init_kernel(WsHeader* ws) {
  unsigned int* p = (unsigned int*)ws;
  const int nw = (int)(sizeof(WsHeader) / 4);
  for (int i = blockIdx.x * blockDim.x + threadIdx.x; i < nw; i += gridDim.x * blockDim.x)
    p[i] = 0u;
}

// Per-cell loss terms + dense key write + top-byte histogram.
// 4 independent cells per thread => 4 overlapped load/compute chains (latency
// hiding); LDS-hist zero/flush and barriers amortized 4x. Direct global loads:
// the stride-20B conf pattern is L1-absorbed (measured: LDS staging neutral, R8).
__global__ __launch_bounds__(256) void main_kernel(const float* __restrict__ pred,
                                                   const float* __restrict__ tgt,
                                                   WsHeader* __restrict__ ws,
                                                   unsigned int* __restrict__ keys) {
  __shared__ float gt[NG * 4];
  __shared__ unsigned int lhist[4 * 257];      // 4 replicas, stride 257
  __shared__ float s_psum, s_rsum;
  __shared__ int s_np;
  const int b = blockIdx.y;
  const int tid = threadIdx.x;
  const int cell0 = blockIdx.x * (256 * CPT);  // 1024 consecutive cells per block

  if (tid < NG * 4) gt[tid] = tgt[b * NG * 4 + tid];
  for (int e = tid; e < 4 * 257; e += 256) lhist[e] = 0u;
  if (tid == 0) { s_psum = 0.f; s_rsum = 0.f; s_np = 0; }
  __syncthreads();

  const float anch[3] = {5.f, 10.f, 20.f};
  const float* pb = pred + (size_t)b * NCELL * 5;

  // issue all CPT conf loads up-front (independent chains)
  float conf[CPT];
#pragma unroll
  for (int j = 0; j < CPT; ++j)
    conf[j] = pb[(size_t)(cell0 + j * 256 + tid) * 5];

#pragma unroll
  for (int j = 0; j < CPT; ++j) {
    const int i = cell0 + j * 256 + tid;
    int a = i % 3; int t = i / 3;
    int w = t % 48; t /= 48;
    int h = t % 48; int d = t / 48;
    const float cx = w * 4.f + 2.f, cy = h * 4.f + 2.f, cz = d * 4.f + 2.f;
    const float an = anch[a];
    const float r1 = an * 0.5f;
    const float an3 = an * an * an;

    float best = -1.f; int arg = 0;
#pragma unroll
    for (int g = 0; g < NG; ++g) {
      float gx = gt[g * 4 + 0], gy = gt[g * 4 + 1], gz = gt[g * 4 + 2], gd = gt[g * 4 + 3];
      float r2 = gd * 0.5f;
      float ix = fmaxf(fminf(cx + r1, gx + r2) - fmaxf(cx - r1, gx - r2), 0.f);
      float iy = fmaxf(fminf(cy + r1, gy + r2) - fmaxf(cy - r1, gy - r2), 0.f);
      float iz = fmaxf(fminf(cz + r1, gz + r2) - fmaxf(cz - r1, gz - r2), 0.f);
      float iv = (ix * iy) * iz;
      float un = (an3 + gd * gd * gd) - iv;
      float iou = iv / (un + 1e-6f);
      if (iou > best) { best = iou; arg = g; }   // strict > == first-argmax
    }
    const bool pos = best > 0.5f;
    const bool neg = best < 0.02f;
    const float cf = conf[j];

    unsigned int key = 0u;   // sentinel: -NaN bit pattern, unreachable as real key
    if (neg) {
      key = f2key(cf);
      atomicAdd(&lhist[(tid & 3) * 257 + (key >> 24)], 1u);
    }
    keys[(size_t)b * NCELL + i] = key;

    if (pos) {
      const size_t base = (size_t)i * 5;
      float bce1 = fmaxf(cf, 0.f) - cf + log1pf(expf(-fabsf(cf)));
      float mgx = gt[arg * 4 + 0], mgy = gt[arg * 4 + 1], mgz = gt[arg * 4 + 2], mgd = gt[arg * 4 + 3];
      float t0 = (mgx - cx) / an, t1 = (mgy - cy) / an, t2 = (mgz - cz) / an;
      float t3 = logf(mgd / an);
      float d0 = pb[base + 1] - t0;
      float d1 = pb[base + 2] - t1;
      float d2 = pb[base + 3] - t2;
      float d3 = pb[base + 4] - t3;
      float rl = sl1(d0) + sl1(d1) + sl1(d2) + sl1(d3);
      atomicAdd(&s_psum, bce1);
      atomicAdd(&s_rsum, rl);
      atomicAdd(&s_np, 1);
    }
  }
  __syncthreads();

  unsigned int c = lhist[tid] + lhist[257 + tid] + lhist[514 + tid] + lhist[771 + tid];
  if (c) atomicAdd(&ws->hist[b][blockIdx.x & (NREP - 1)][tid], c);
  if (tid == 0 && s_np > 0) {        // rare: fire-and-forget, most blocks skip
    atomicAdd(&ws->pos_sum[b], s_psum);
    atomicAdd(&ws->reg_sum[b], s_rsum);
    atomicAdd(&ws->npos[b], s_np);
  }
}

// Grid-parallel: each block redundantly finds the 8-bit threshold bucket j from
// the histogram, then compacts keys with top8 >= j into the small bucket buffer.
// Publishes j and k_rem so final can skip its degenerate radix pass 0.
__global__ __launch_bounds__(256) void compact_kernel(const unsigned int* __restrict__ keys,
                                                      WsHeader* __restrict__ ws,
                                                      unsigned int* __restrict__ bucket) {
  const int b = blockIdx.y;
  const int tid = threadIdx.x;
  __shared__ unsigned int A[256];
  __shared__ unsigned int cnts[256];
  __shared__ int sh_j, sh_base;

  unsigned int s = 0;
#pragma unroll
  for (int r = 0; r < NREP; ++r) s += ws->hist[b][r][tid];
  A[tid] = s;
  __syncthreads();
  for (int dlt = 1; dlt < 256; dlt <<= 1) {   // inclusive suffix scan
    unsigned int v = (tid + dlt < 256) ? A[tid + dlt] : 0u;
    __syncthreads();
    A[tid] += v;
    __syncthreads();
  }
  const int M = (int)A[0];
  const bool ta = (M < KTOP);
  if (!ta && A[tid] >= (unsigned)KTOP && (tid == 255 || A[tid + 1] < (unsigned)KTOP))
    sh_j = tid;
  __syncthreads();
  const unsigned int jthr = ta ? 0u : (unsigned int)sh_j;
  if (tid == 0 && blockIdx.x == 0) {
    ws->neg_cnt[b] = M;
    ws->take_all[b] = ta ? 1 : 0;
    ws->prefix8[b] = (int)jthr;
    int above = (!ta && jthr < 255u) ? (int)A[jthr + 1] : 0;
    ws->k_rem[b] = ta ? 0 : (KTOP - above);
  }

  const uint4* k4 = (const uint4*)(keys + (size_t)b * NCELL);
  const int base4 = blockIdx.x * 1024;   // 81 blocks x 1024 uint4 = NCELL/4
  int cnt = 0;
#pragma unroll
  for (int it = 0; it < 4; ++it) {
    uint4 kk = k4[base4 + it * 256 + tid];
    cnt += (kk.x != 0u && (kk.x >> 24) >= jthr);
    cnt += (kk.y != 0u && (kk.y >> 24) >= jthr);
    cnt += (kk.z != 0u && (kk.z >> 24) >= jthr);
    cnt += (kk.w != 0u && (kk.w >> 24) >= jthr);
  }
  cnts[tid] = (unsigned int)cnt;
  __syncthreads();
  for (int dlt = 1; dlt < 256; dlt <<= 1) {   // inclusive prefix scan
    unsigned int v = (tid >= dlt) ? cnts[tid - dlt] : 0u;
    __syncthreads();
    cnts[tid] += v;
    __syncthreads();
  }
  if (tid == 255) {
    int total = (int)cnts[255];
    sh_base = total ? atomicAdd(&ws->bucket_cnt[b][0], total) : 0;
  }
  __syncthreads();
  int off = sh_base + (int)cnts[tid] - cnt;   // exclusive rank + block base
#pragma unroll
  for (int it = 0; it < 4; ++it) {
    uint4 kk = k4[base4 + it * 256 + tid];
    unsigned int kv;
    kv = kk.x; if (kv != 0u && (kv >> 24) >= jthr) { if (off < CAP) bucket[(size_t)b * CAP + off] = kv; ++off; }
    kv = kk.y; if (kv != 0u && (kv >> 24) >= jthr) { if (off < CAP) bucket[(size_t)b * CAP + off] = kv; ++off; }
    kv = kk.z; if (kv != 0u && (kv >> 24) >= jthr) { if (off < CAP) bucket[(size_t)b * CAP + off] = kv; ++off; }
    kv = kk.w; if (kv != 0u && (kv >> 24) >= jthr) { if (off < CAP) bucket[(size_t)b * CAP + off] = kv; ++off; }
  }
}

// One block per batch: exact top-KTOP among the ~7.4k candidates.
// Radix starts at pass 1 (pass-0 bucket j + k_rem come from compact), candidates
// cached in LDS. Last block to finish also does the final combine.
__global__ __launch_bounds__(1024) void final_kernel(const unsigned int* __restrict__ bucket,
                                                     WsHeader* __restrict__ ws,
                                                     float* __restrict__ out) {
  const int b = blockIdx.x;
  const int tid = threadIdx.x;
  __shared__ unsigned int skeys[LCAP];
  __shared__ unsigned int h[256];
  __shared__ unsigned int A[256];
  __shared__ int sh_j;
  __shared__ float wred[16];
  __shared__ int sh_last;

  int m = ws->bucket_cnt[b][0]; if (m > CAP) m = CAP;
  const bool ta = ws->take_all[b] != 0;
  const unsigned int* kb = bucket + (size_t)b * CAP;
  const bool useLds = (m <= LCAP);
  if (useLds)
    for (int i = tid; i < m; i += 1024) skeys[i] = kb[i];
  __syncthreads();

  unsigned int T = 0u;
  int k = 0;
  if (!ta) {
    unsigned int P = ((unsigned int)ws->prefix8[b]) << 24;
    k = ws->k_rem[b];
    for (int pass = 1; pass < 4; ++pass) {
      const int sh = 24 - 8 * pass;
      const unsigned int hiMask = 0xFFFFFFFFu << (sh + 8);
      if (tid < 256) h[tid] = 0u;
      __syncthreads();
      for (int i = tid; i < m; i += 1024) {
        unsigned int kv = useLds ? skeys[i] : kb[i];
        if (((kv ^ P) & hiMask) == 0u) atomicAdd(&h[(kv >> sh) & 255u], 1u);
      }
      __syncthreads();
      if (tid < 256) A[tid] = h[tid];
      __syncthreads();
      for (int dlt = 1; dlt < 256; dlt <<= 1) {
        unsigned int v = (tid < 256 && tid + dlt < 256) ? A[tid + dlt] : 0u;
        __syncthreads();
        if (tid < 256) A[tid] += v;
        __syncthreads();
      }
      if (tid < 256 && A[tid] >= (unsigned)k && (tid == 255 || A[tid + 1] < (unsigned)k))
        sh_j = tid;
      __syncthreads();
      const int j = sh_j;
      k -= (j == 255) ? 0 : (int)A[j + 1];   // remove strictly-greater bins
      P |= ((unsigned int)j) << sh;
      __syncthreads();
    }
    T = P;   // exact threshold key; k = #ties to take at T
  }

  float v = 0.f;
  for (int i = tid; i < m; i += 1024) {
    unsigned int kv = useLds ? skeys[i] : kb[i];
    if (ta || kv > T) v += softplus0(key2f(kv));
  }
  for (int o = 32; o > 0; o >>= 1) v += __shfl_down(v, o);
  if ((tid & 63) == 0) wred[tid >> 6] = v;
  __syncthreads();
  if (tid == 0) {
    float sum = 0.f;
#pragma unroll
    for (int wv = 0; wv < 16; ++wv) sum += wred[wv];
    if (!ta) sum += (float)k * softplus0(key2f(T));
    ws->neg_sum[b] = sum;
    __threadfence();
    int old = atomicAdd(&ws->done, 1);
    sh_last = (old == NB - 1) ? 1 : 0;
  }
  __syncthreads();
  if (sh_last && tid == 0) {
    __threadfence();
    float cls_s = 0.f, reg_s = 0.f, np_s = 0.f;
    for (int bb = 0; bb < NB; ++bb) {
      int np = ws->npos[bb];
      float pos_l = (np > 0) ? 5.f * ws->pos_sum[bb] / (float)np : 0.f;
      int M = ws->neg_cnt[bb];
      float kcnt = fminf((float)M, (float)KTOP);
      float neg_l = (kcnt > 0.f) ? ws->neg_sum[bb] / fmaxf(kcnt, 1.f) : 0.f;
      float reg_l = (np > 0) ? ws->reg_sum[bb] / (4.f * (float)np) : 0.f;
      cls_s += pos_l + neg_l;
      reg_s += reg_l;
      np_s += (float)np;
    }
    float cls = cls_s * 0.25f;
    float reg = reg_s * 0.25f;
    out[0] = cls + 0.5f * reg;
    out[1] = cls;
    out[2] = reg;
    out[3] = np_s;
  }
}

extern "C" void kernel_launch(void* const* d_in, const int* in_sizes, int n_in,
                              void* d_out, int out_size, void* d_ws, size_t ws_size,
                              hipStream_t stream) {
  const float* pred = (const float*)d_in[0];
  const float* tgt  = (const float*)d_in[1];
  WsHeader* ws = (WsHeader*)d_ws;
  char* base = (char*)d_ws + ((sizeof(WsHeader) + 255) / 256) * 256;
  unsigned int* keys = (unsigned int*)base;
  unsigned int* bucket = (unsigned int*)(base + (size_t)NB * NCELL * 4);
  float* out = (float*)d_out;

  hipLaunchKernelGGL(init_kernel, dim3(16), dim3(256), 0, stream, ws);
  hipLaunchKernelGGL(main_kernel, dim3(MBLK, NB), dim3(256), 0, stream, pred, tgt, ws, keys);
  hipLaunchKernelGGL(compact_kernel, dim3(81, NB), dim3(256), 0, stream, keys, ws, bucket);
  hipLaunchKernelGGL(final_kernel, dim3(NB), dim3(1024), 0, stream, bucket, ws, out);
}